// Round 3
// baseline (257.547 us; speedup 1.0000x reference)
//
#include <hip/hip_runtime.h>
#include <hip/hip_bf16.h>

// Problem constants: B=4 S=8192 D=1024 K=1024, TAU=1.0
constexpr int MM   = 32768;    // B*S
constexpr int NN   = 1024;     // output cols of both GEMMs
constexpr int KRED = 1024;     // reduction dim
constexpr int LDAB = KRED * 2; // bytes per bf16 row of A / Bt

using s16x8 = __attribute__((ext_vector_type(8))) short;
using f32x4 = __attribute__((ext_vector_type(4))) float;

__device__ __forceinline__ unsigned short f2bf(float f) {
  unsigned u = __float_as_uint(f);
  return (unsigned short)((u + 0x7fffu + ((u >> 16) & 1u)) >> 16);
}

__device__ __forceinline__ void gload_lds16(const void* g, void* l) {
  __builtin_amdgcn_global_load_lds(
      (const __attribute__((address_space(1))) void*)g,
      (__attribute__((address_space(3))) void*)l, 16, 0, 0);
}

__device__ __forceinline__ float wave_sum(float v) {
#pragma unroll
  for (int o = 32; o > 0; o >>= 1) v += __shfl_xor(v, o);
  return v;
}
__device__ __forceinline__ float wave_max(float v) {
#pragma unroll
  for (int o = 32; o > 0; o >>= 1) v = fmaxf(v, __shfl_xor(v, o));
  return v;
}

// ---------------------------------------------------------------------------
// prep_cb: one block per codebook row k (tiny: 1024 blocks). Produces CB
// (bf16 [K,D]), CT (bf16 [D,K]), c2[k] (f32, exact from f32 input).
// ---------------------------------------------------------------------------
__global__ __launch_bounds__(256) void prep_cb(const float* __restrict__ C,
                                               unsigned short* __restrict__ CB,
                                               unsigned short* __restrict__ CT,
                                               float* __restrict__ c2) {
  int k = blockIdx.x;
  int t = threadIdx.x;
  const float4 v = *(const float4*)(C + (size_t)k * 1024 + t * 4);
  ushort4 b = make_ushort4(f2bf(v.x), f2bf(v.y), f2bf(v.z), f2bf(v.w));
  *(ushort4*)(CB + (size_t)k * 1024 + t * 4) = b;
  CT[(size_t)(t * 4 + 0) * 1024 + k] = b.x;
  CT[(size_t)(t * 4 + 1) * 1024 + k] = b.y;
  CT[(size_t)(t * 4 + 2) * 1024 + k] = b.z;
  CT[(size_t)(t * 4 + 3) * 1024 + k] = b.w;
  float p = v.x * v.x + v.y * v.y + v.z * v.z + v.w * v.w;
  p = wave_sum(p);
  __shared__ float red[4];
  if ((t & 63) == 0) red[t >> 6] = p;
  __syncthreads();
  if (t == 0) c2[k] = red[0] + red[1] + red[2] + red[3];
}

// ---------------------------------------------------------------------------
// prep_x: wave-per-row, no LDS, no barriers. 512-thr blocks, 8 rows/block.
// Produces Xb (bf16 [M,D]) and x2[m] (f32, from the ORIGINAL f32 data).
// ---------------------------------------------------------------------------
__global__ __launch_bounds__(512) void prep_x(const float* __restrict__ X,
                                              unsigned short* __restrict__ Xb,
                                              float* __restrict__ x2) {
  int tid = threadIdx.x;
  int l = tid & 63, w = tid >> 6;
  int m = blockIdx.x * 8 + w;
  size_t base = (size_t)m * 1024 + l * 4;
  float p = 0.0f;
#pragma unroll
  for (int j = 0; j < 4; ++j) {
    const float4 v = *(const float4*)(X + base + j * 256);
    *(ushort4*)(Xb + base + j * 256) =
        make_ushort4(f2bf(v.x), f2bf(v.y), f2bf(v.z), f2bf(v.w));
    p += v.x * v.x + v.y * v.y + v.z * v.z + v.w * v.w;
  }
  p = wave_sum(p);
  if (l == 0) x2[m] = p;
}

// ---------------------------------------------------------------------------
// softmax: wave-per-row, no LDS, no barriers. 512-thr blocks, 8 rows/block.
// w = softmax(logits + gumbel(noise)) (TAU=1), bf16 into W.
// Inner logf kept accurate (u->1 cancellation feeds the DOMINANT gumbel);
// outer __logf / __expf are fast-path (1e-6-rel errors, harmless).
// ---------------------------------------------------------------------------
__global__ __launch_bounds__(512) void softmax_k(const float* __restrict__ logits,
                                                 const float* __restrict__ noise,
                                                 unsigned short* __restrict__ W) {
  int tid = threadIdx.x;
  int l = tid & 63, w = tid >> 6;
  int m = blockIdx.x * 8 + w;
  size_t base = (size_t)m * 1024 + l * 4;

  float s[16];
  float mx = -3.0e38f;
#pragma unroll
  for (int j = 0; j < 4; ++j) {
    const float4 lv = *(const float4*)(logits + base + j * 256);
    const float4 nv = *(const float4*)(noise + base + j * 256);
    s[j * 4 + 0] = lv.x - __logf(-logf(nv.x));
    s[j * 4 + 1] = lv.y - __logf(-logf(nv.y));
    s[j * 4 + 2] = lv.z - __logf(-logf(nv.z));
    s[j * 4 + 3] = lv.w - __logf(-logf(nv.w));
    mx = fmaxf(mx, fmaxf(fmaxf(s[j * 4], s[j * 4 + 1]),
                         fmaxf(s[j * 4 + 2], s[j * 4 + 3])));
  }
  mx = wave_max(mx);

  float ps = 0.0f;
#pragma unroll
  for (int i = 0; i < 16; ++i) {
    s[i] = __expf(s[i] - mx);
    ps += s[i];
  }
  ps = wave_sum(ps);
  float inv = 1.0f / ps;

#pragma unroll
  for (int j = 0; j < 4; ++j) {
    *(ushort4*)(W + base + j * 256) =
        make_ushort4(f2bf(s[j * 4 + 0] * inv), f2bf(s[j * 4 + 1] * inv),
                     f2bf(s[j * 4 + 2] * inv), f2bf(s[j * 4 + 3] * inv));
  }
}

// ---------------------------------------------------------------------------
// gemm256<MODE>: UNCHANGED from the passing round-2 kernel.
// 256x256 tile, BK=64, 8 waves, 8-phase schedule, counted vmcnt,
// T2 row-XOR LDS swizzle, T5 setprio. out = A @ Bt^T (bf16 in, f32 out).
// MODE==1: epilogue v -> -sqrt(max(x2[row]+c2[col]-2v,0)).
// ---------------------------------------------------------------------------
template <int MODE>
__global__ __launch_bounds__(512, 2) void gemm256(const unsigned short* __restrict__ A,
                                                  const unsigned short* __restrict__ Bt,
                                                  float* __restrict__ out,
                                                  const float* __restrict__ x2,
                                                  const float* __restrict__ c2) {
  extern __shared__ char smem[];

  int bid = blockIdx.x;                     // 512 blocks
  int swz = (bid & 7) * 64 + (bid >> 3);    // XCD swizzle (512 % 8 == 0)
  int bm = swz >> 2, bn = swz & 3;
  int brow0 = bm * 256, bcol0 = bn * 256;

  int tid = threadIdx.x;
  int l = tid & 63, w = tid >> 6;           // 8 waves
  int wm = w >> 2, wn = w & 3;              // 2x4 wave grid; per-wave 128x64
  int lr = l & 15, lh = l >> 4;
  const int xsw = (lr & 7) << 4;

  const char* AbH[2] = { (const char*)A + (size_t)brow0 * LDAB,
                         (const char*)A + (size_t)(brow0 + 128) * LDAB };
  const char* BbH[2] = { (const char*)Bt + (size_t)bcol0 * LDAB,
                         (const char*)Bt + (size_t)(bcol0 + 128) * LDAB };

  const int sr0 = tid >> 3;
  const int sc  = (tid & 7) * 16;
  const int scx0 = sc ^ ((sr0 & 7) << 4);

#define STAGE(gbase, kbyte, ldsreg)                                            \
  do {                                                                         \
    gload_lds16((gbase) + (size_t)sr0 * LDAB + (kbyte) + scx0,                 \
                (ldsreg) + tid * 16);                                          \
    gload_lds16((gbase) + (size_t)(sr0 + 64) * LDAB + (kbyte) + scx0,          \
                (ldsreg) + 8192 + tid * 16);                                   \
  } while (0)

  STAGE(AbH[0], 0, smem + 0);
  STAGE(AbH[1], 0, smem + 16384);
  STAGE(BbH[0], 0, smem + 32768);
  STAGE(BbH[1], 0, smem + 49152);
  STAGE(BbH[0], 128, smem + 65536 + 32768);
  STAGE(BbH[1], 128, smem + 65536 + 49152);
  asm volatile("s_waitcnt vmcnt(4)" ::: "memory");
  __builtin_amdgcn_s_barrier();

  const int aoff0 = wm * 16384 + lr * 128;
  const int boff0 = (wn >> 1) * 16384 + (wn & 1) * 8192 + lr * 128;

  f32x4 acc[8][4] = {};
  s16x8 af[4][2], bf[4][2];

#pragma unroll 2
  for (int t = 0; t < 16; ++t) {
    int p = t & 1;
    char* As  = smem + p * 65536;
    char* Bs  = smem + p * 65536 + 32768;
    char* Asn = smem + (1 - p) * 65536;

    // ---- P1
#pragma unroll
    for (int mi = 0; mi < 4; ++mi)
#pragma unroll
      for (int ks = 0; ks < 2; ++ks)
        af[mi][ks] = *(const s16x8*)(As + aoff0 + mi * 2048 + ((ks * 64 + lh * 16) ^ xsw));
#pragma unroll
    for (int ni = 0; ni < 2; ++ni)
#pragma unroll
      for (int ks = 0; ks < 2; ++ks)
        bf[ni][ks] = *(const s16x8*)(Bs + boff0 + ni * 2048 + ((ks * 64 + lh * 16) ^ xsw));
    if (t + 1 < 16) STAGE(AbH[0], (t + 1) * 128, Asn + 0);
    __builtin_amdgcn_s_barrier();
    asm volatile("s_waitcnt lgkmcnt(0)" ::: "memory");
    __builtin_amdgcn_sched_barrier(0);
    __builtin_amdgcn_s_setprio(1);
#pragma unroll
    for (int mi = 0; mi < 4; ++mi)
#pragma unroll
      for (int ni = 0; ni < 2; ++ni)
#pragma unroll
        for (int ks = 0; ks < 2; ++ks)
          acc[mi][ni] = __builtin_amdgcn_mfma_f32_16x16x32_bf16(af[mi][ks], bf[ni][ks], acc[mi][ni], 0, 0, 0);
    __builtin_amdgcn_s_setprio(0);
    __builtin_amdgcn_s_barrier();

    // ---- P2
#pragma unroll
    for (int ni = 0; ni < 2; ++ni)
#pragma unroll
      for (int ks = 0; ks < 2; ++ks)
        bf[2 + ni][ks] = *(const s16x8*)(Bs + boff0 + (2 + ni) * 2048 + ((ks * 64 + lh * 16) ^ xsw));
    if (t + 1 < 16) STAGE(AbH[1], (t + 1) * 128, Asn + 16384);
    __builtin_amdgcn_s_barrier();
    asm volatile("s_waitcnt lgkmcnt(0)" ::: "memory");
    __builtin_amdgcn_sched_barrier(0);
    __builtin_amdgcn_s_setprio(1);
#pragma unroll
    for (int mi = 0; mi < 4; ++mi)
#pragma unroll
      for (int ni = 0; ni < 2; ++ni)
#pragma unroll
        for (int ks = 0; ks < 2; ++ks)
          acc[mi][2 + ni] = __builtin_amdgcn_mfma_f32_16x16x32_bf16(af[mi][ks], bf[2 + ni][ks], acc[mi][2 + ni], 0, 0, 0);
    __builtin_amdgcn_s_setprio(0);
    __builtin_amdgcn_s_barrier();

    // ---- P3
#pragma unroll
    for (int mi = 0; mi < 4; ++mi)
#pragma unroll
      for (int ks = 0; ks < 2; ++ks)
        af[mi][ks] = *(const s16x8*)(As + aoff0 + (4 + mi) * 2048 + ((ks * 64 + lh * 16) ^ xsw));
    if (t + 2 < 16) STAGE(BbH[0], (t + 2) * 128, Bs + 0);
    __builtin_amdgcn_s_barrier();
    asm volatile("s_waitcnt lgkmcnt(0)" ::: "memory");
    __builtin_amdgcn_sched_barrier(0);
    __builtin_amdgcn_s_setprio(1);
#pragma unroll
    for (int mi = 0; mi < 4; ++mi)
#pragma unroll
      for (int ni = 0; ni < 2; ++ni)
#pragma unroll
        for (int ks = 0; ks < 2; ++ks)
          acc[4 + mi][ni] = __builtin_amdgcn_mfma_f32_16x16x32_bf16(af[mi][ks], bf[ni][ks], acc[4 + mi][ni], 0, 0, 0);
    __builtin_amdgcn_s_setprio(0);
    __builtin_amdgcn_s_barrier();

    // ---- P4
    if (t + 2 < 16) STAGE(BbH[1], (t + 2) * 128, Bs + 16384);
    __builtin_amdgcn_s_setprio(1);
#pragma unroll
    for (int mi = 0; mi < 4; ++mi)
#pragma unroll
      for (int ni = 0; ni < 2; ++ni)
#pragma unroll
        for (int ks = 0; ks < 2; ++ks)
          acc[4 + mi][2 + ni] = __builtin_amdgcn_mfma_f32_16x16x32_bf16(af[mi][ks], bf[2 + ni][ks], acc[4 + mi][2 + ni], 0, 0, 0);
    __builtin_amdgcn_s_setprio(0);
    __builtin_amdgcn_sched_barrier(0);
    if (t < 14) { asm volatile("s_waitcnt vmcnt(4)" ::: "memory"); }
    else        { asm volatile("s_waitcnt vmcnt(0)" ::: "memory"); }
    __builtin_amdgcn_s_barrier();
  }
#undef STAGE

#pragma unroll
  for (int mi = 0; mi < 8; ++mi) {
    int row0 = brow0 + wm * 128 + mi * 16 + lh * 4;
#pragma unroll
    for (int r = 0; r < 4; ++r) {
      int row = row0 + r;
      float xv = (MODE == 1) ? x2[row] : 0.0f;
#pragma unroll
      for (int ni = 0; ni < 4; ++ni) {
        int col = bcol0 + wn * 64 + ni * 16 + lr;
        float v = acc[mi][ni][r];
        if (MODE == 1) {
          float d2 = xv + c2[col] - 2.0f * v;
          v = -sqrtf(fmaxf(d2, 0.0f));
        }
        out[(size_t)row * NN + col] = v;
      }
    }
  }
}

// ---------------------------------------------------------------------------
extern "C" void kernel_launch(void* const* d_in, const int* in_sizes, int n_in,
                              void* d_out, int out_size, void* d_ws, size_t ws_size,
                              hipStream_t stream) {
  const float* emb   = (const float*)d_in[0];
  const float* cb    = (const float*)d_in[1];
  const float* noise = (const float*)d_in[2];

  float* quant  = (float*)d_out;
  float* logits = (float*)d_out + (size_t)MM * NN;

  char* ws = (char*)d_ws;
  unsigned short* XW = (unsigned short*)ws;               // 64 MiB X/W bf16
  unsigned short* CB = (unsigned short*)(ws + 67108864);  // 2 MiB
  unsigned short* CT = (unsigned short*)(ws + 69206016);  // 2 MiB
  float* x2 = (float*)(ws + 71303168);                    // 128 KiB
  float* c2 = (float*)(ws + 71434240);                    // 4 KiB

  static bool attr_done = false;
  if (!attr_done) {
    hipFuncSetAttribute((const void*)gemm256<1>,
                        hipFuncAttributeMaxDynamicSharedMemorySize, 131072);
    hipFuncSetAttribute((const void*)gemm256<0>,
                        hipFuncAttributeMaxDynamicSharedMemorySize, 131072);
    attr_done = true;
  }

  prep_cb<<<dim3(1024), dim3(256), 0, stream>>>(cb, CB, CT, c2);
  prep_x<<<dim3(MM / 8), dim3(512), 0, stream>>>(emb, XW, x2);
  gemm256<1><<<dim3(512), dim3(512), 131072, stream>>>(XW, CB, logits, x2, c2);
  softmax_k<<<dim3(MM / 8), dim3(512), 0, stream>>>(logits, noise, XW);
  gemm256<0><<<dim3(512), dim3(512), 131072, stream>>>(XW, CT, quant, nullptr, nullptr);
}